// Round 1
// baseline (397.333 us; speedup 1.0000x reference)
//
#include <hip/hip_runtime.h>

// Conv1dFFTInt8: B=16, CIN=128, COUT=128, L=4096, out_size==1.
// Identity: ifft(sum_l X[l]W[l])[0] = sum_n x[n] * w[(L-n) mod L]  (real inputs)
// => out[b,o] = bias[o] + sum_i sum_m w[o,i,m] * x[b,i,(L-m)&(L-1)]
// Pure HBM-bound dot products: weight 256MB read once, x 32MB (L3-resident,
// re-staged once per o-tile of 16).

constexpr int LEN   = 4096;
constexpr int CIN_  = 128;
constexpr int COUT_ = 128;
constexpr int BATCH = 16;

__global__ void init_out_kernel(const float* __restrict__ bias, float* __restrict__ out) {
    int t = blockIdx.x * 256 + threadIdx.x;
    if (t < BATCH * COUT_) out[t] = bias[t & (COUT_ - 1)];
}

// Block: 256 threads = 4 waves. Each block: o-tile of 16 (4 per wave),
// 8 K-chunks of 1024 (K = ci*4096 + m). Grid = 8 o-tiles * 64 k-groups = 512.
__global__ __launch_bounds__(256, 2)
void conv_fft_dot_kernel(const float* __restrict__ x, const float* __restrict__ w,
                         float* __restrict__ out) {
    // 16*1024 floats for staged x; reused as 4*64*68 padded reduce area.
    __shared__ float lds[17408];

    const int tid   = threadIdx.x;
    const int lane  = tid & 63;
    const int wv    = tid >> 6;
    const int bk    = blockIdx.x;   // 0..511
    const int ot    = bk >> 6;      // 0..7   o-tile
    const int kg    = bk & 63;      // 0..63  k-group (8 chunks each)
    const int obase = ot * 16 + wv * 4;

    float acc[16][4];
#pragma unroll
    for (int b = 0; b < 16; ++b)
#pragma unroll
        for (int j = 0; j < 4; ++j) acc[b][j] = 0.f;

    for (int q = 0; q < 8; ++q) {
        const int kc = kg * 8 + q;       // chunk id 0..511
        const int ci = kc >> 2;          // input channel
        const int m0 = (kc & 3) << 10;   // m offset within channel

        __syncthreads();  // previous chunk's readers done
        // ---- stage x[b, ci, (LEN - m0 - mm) & 4095] -> lds[b*1024 + mm]
        {
            const int nbase = LEN - m0 - tid;
#pragma unroll
            for (int b = 0; b < 16; ++b) {
                const float* xp = x + ((b * CIN_ + ci) << 12);
                float* lp = lds + (b << 10) + tid;
#pragma unroll
                for (int p = 0; p < 4; ++p) {
                    int n = (nbase - (p << 8)) & (LEN - 1);
                    lp[p << 8] = xp[n];   // descending-coalesced global read
                }
            }
        }
        __syncthreads();

        // ---- compute: weight streamed as coalesced float4, one read each
        const float4* wp0 = (const float4*)(w + (((obase + 0) * CIN_ + ci) << 12) + m0);
        const float4* wp1 = (const float4*)(w + (((obase + 1) * CIN_ + ci) << 12) + m0);
        const float4* wp2 = (const float4*)(w + (((obase + 2) * CIN_ + ci) << 12) + m0);
        const float4* wp3 = (const float4*)(w + (((obase + 3) * CIN_ + ci) << 12) + m0);

        float4 wr[4];
        wr[0] = wp0[lane]; wr[1] = wp1[lane]; wr[2] = wp2[lane]; wr[3] = wp3[lane];
#pragma unroll
        for (int s = 0; s < 4; ++s) {
            float4 wn[4];
            if (s < 3) {   // one-step lookahead prefetch of next weight quad
                const int off = (s + 1) * 64 + lane;
                wn[0] = wp0[off]; wn[1] = wp1[off]; wn[2] = wp2[off]; wn[3] = wp3[off];
            }
            const float4* xls = (const float4*)lds + s * 64 + lane;
#pragma unroll
            for (int b = 0; b < 16; ++b) {
                float4 xv = xls[b << 8];   // ds_read_b128, conflict-free
#pragma unroll
                for (int j = 0; j < 4; ++j) {
                    acc[b][j] += xv.x * wr[j].x;
                    acc[b][j] += xv.y * wr[j].y;
                    acc[b][j] += xv.z * wr[j].z;
                    acc[b][j] += xv.w * wr[j].w;
                }
            }
            if (s < 3) { wr[0] = wn[0]; wr[1] = wn[1]; wr[2] = wn[2]; wr[3] = wn[3]; }
        }
    }

    // ---- cross-lane reduction via padded LDS transpose (rows of 68 floats)
    __syncthreads();
#pragma unroll
    for (int b = 0; b < 16; ++b)
#pragma unroll
        for (int j = 0; j < 4; ++j)
            lds[(wv * 64 + b * 4 + j) * 68 + lane] = acc[b][j];
    __syncthreads();
    {
        const int wv2 = tid >> 6, st = tid & 63;
        const float4* row = (const float4*)(lds + (wv2 * 64 + st) * 68);
        float sum = 0.f;
#pragma unroll
        for (int l = 0; l < 16; ++l) {
            float4 v = row[l];
            sum += v.x + v.y + v.z + v.w;
        }
        const int b = st >> 2, j = st & 3;
        const int o = ot * 16 + wv2 * 4 + j;
        atomicAdd(out + b * COUT_ + o, sum);
    }
}

extern "C" void kernel_launch(void* const* d_in, const int* in_sizes, int n_in,
                              void* d_out, int out_size, void* d_ws, size_t ws_size,
                              hipStream_t stream) {
    const float* x    = (const float*)d_in[0];   // [16,128,4096]
    const float* wgt  = (const float*)d_in[1];   // [128,128,4096]
    const float* bias = (const float*)d_in[2];   // [128]
    float* out = (float*)d_out;                  // [16,128,1]
    (void)in_sizes; (void)n_in; (void)d_ws; (void)ws_size; (void)out_size;

    init_out_kernel<<<8, 256, 0, stream>>>(bias, out);
    conv_fft_dot_kernel<<<512, 256, 0, stream>>>(x, wgt, out);
}